// Round 1
// baseline (100.495 us; speedup 1.0000x reference)
//
#include <hip/hip_runtime.h>

#define MARGIN 1.0f

__device__ __forceinline__ float wave_reduce_sum(float v) {
    #pragma unroll
    for (int off = 32; off > 0; off >>= 1)
        v += __shfl_down(v, off, 64);
    return v;
}

// loss_cls partial: sum over (o - one_hot(y))^2, atomicAdd into ws[0]
__global__ void cls_kernel(const float* __restrict__ o, const int* __restrict__ y,
                           float* __restrict__ ws, int B, int C) {
    int q = blockIdx.x * blockDim.x + threadIdx.x;   // one float4 per thread
    int nq = B * C / 4;                              // C % 4 == 0 so a float4 never crosses a row
    float acc = 0.f;
    if (q < nq) {
        int perRow = C >> 2;
        int b  = q / perRow;
        int c0 = (q - b * perRow) * 4;
        float4 v = reinterpret_cast<const float4*>(o)[q];
        int yb = y[b];
        float d0 = v.x - ((c0 + 0 == yb) ? 1.f : 0.f);
        float d1 = v.y - ((c0 + 1 == yb) ? 1.f : 0.f);
        float d2 = v.z - ((c0 + 2 == yb) ? 1.f : 0.f);
        float d3 = v.w - ((c0 + 3 == yb) ? 1.f : 0.f);
        acc = d0*d0 + d1*d1 + d2*d2 + d3*d3;
    }
    acc = wave_reduce_sum(acc);
    if ((threadIdx.x & 63) == 0)
        atomicAdd(&ws[0], acc);
}

// loss_close partials: per-class sum of ||z[b, y_b, :] - w[y_b, :]||^2 and counts
// ws[2 + c] = sums, ws[2 + C + c] = counts
__global__ void close_kernel(const float* __restrict__ z, const float* __restrict__ w,
                             const int* __restrict__ y, float* __restrict__ ws,
                             int B, int C, int D) {
    int wid  = threadIdx.x >> 6;
    int lane = threadIdx.x & 63;
    int b = blockIdx.x * (blockDim.x >> 6) + wid;    // one wave64 per sample
    if (b >= B) return;
    int yb = y[b];
    const float2* zp = reinterpret_cast<const float2*>(z + ((size_t)b * C + yb) * D);
    const float2* wp = reinterpret_cast<const float2*>(w + (size_t)yb * D);
    float2 zv = zp[lane];   // 64 lanes x float2 = 128 floats = D, coalesced
    float2 wv = wp[lane];
    float d0 = zv.x - wv.x;
    float d1 = zv.y - wv.y;
    float acc = d0*d0 + d1*d1;
    acc = wave_reduce_sum(acc);
    if (lane == 0) {
        atomicAdd(&ws[2 + yb], acc);
        atomicAdd(&ws[2 + C + yb], 1.0f);
    }
}

// loss_dist partial: block i computes S[i] = sum_j ||w[j]-w[i]||^2 / ((C-1)*D),
// adds relu(MARGIN - S)/C into ws[1]
__global__ void dist_kernel(const float* __restrict__ w, float* __restrict__ ws,
                            int C, int D) {
    int i = blockIdx.x;
    int d = threadIdx.x;          // blockDim.x == D == 128
    float wi = w[i * D + d];
    float acc = 0.f;
    for (int j = 0; j < C; ++j) {
        float v = w[j * D + d] - wi;
        acc += v * v;
    }
    acc = wave_reduce_sum(acc);
    __shared__ float part[2];
    if ((threadIdx.x & 63) == 0) part[threadIdx.x >> 6] = acc;
    __syncthreads();
    if (threadIdx.x == 0) {
        float S = (part[0] + part[1]) / ((float)(C - 1) * (float)D);
        float contrib = fmaxf(MARGIN - S, 0.f) / (float)C;
        atomicAdd(&ws[1], contrib);
    }
}

// combine: out = [total, loss_cls, loss_close, loss_dist]
__global__ void final_kernel(const float* __restrict__ ws, float* __restrict__ out,
                             int B, int C, int D) {
    int lane = threadIdx.x;       // 64 threads
    float closeAcc = 0.f;
    for (int c = lane; c < C; c += 64) {
        float s = ws[2 + c];
        float n = ws[2 + C + c];
        closeAcc += s / (n * (float)D);
    }
    closeAcc = wave_reduce_sum(closeAcc);
    if (lane == 0) {
        float loss_cls   = ws[0] / ((float)B * (float)C);
        float loss_close = closeAcc;
        float loss_dist  = ws[1];
        out[0] = loss_cls + loss_close + loss_dist;
        out[1] = loss_cls;
        out[2] = loss_close;
        out[3] = loss_dist;
    }
}

extern "C" void kernel_launch(void* const* d_in, const int* in_sizes, int n_in,
                              void* d_out, int out_size, void* d_ws, size_t ws_size,
                              hipStream_t stream) {
    const float* z = (const float*)d_in[0];
    const float* w = (const float*)d_in[1];
    const float* o = (const float*)d_in[2];
    const int*   y = (const int*)d_in[3];
    float* out = (float*)d_out;
    float* ws  = (float*)d_ws;

    const int B = in_sizes[3];              // 8192
    const int C = in_sizes[2] / B;          // 100
    const int D = in_sizes[1] / C;          // 128

    // zero accumulators: ws[0]=cls, ws[1]=dist, ws[2..2+C)=close sums, ws[2+C..2+2C)=counts
    hipMemsetAsync(ws, 0, (size_t)(2 + 2 * C) * sizeof(float), stream);

    int nq = B * C / 4;
    cls_kernel<<<(nq + 255) / 256, 256, 0, stream>>>(o, y, ws, B, C);
    close_kernel<<<(B + 3) / 4, 256, 0, stream>>>(z, w, y, ws, B, C, D);
    dist_kernel<<<C, D, 0, stream>>>(w, ws, C, D);
    final_kernel<<<1, 64, 0, stream>>>(ws, out, B, C, D);
}

// Round 2
// 55.553 us; speedup vs baseline: 1.8090x; 1.8090x over previous
//
#include <hip/hip_runtime.h>

#define MARGIN 1.0f

__device__ __forceinline__ float wave_reduce_sum(float v) {
    #pragma unroll
    for (int off = 32; off > 0; off >>= 1)
        v += __shfl_down(v, off, 64);
    return v;
}

// ws layout:
//   ws[0]                : loss_dist (written by K0)
//   ws[1 + c],     c<C   : close per-class sums   (atomic, zeroed by K0)
//   ws[1 + C + c], c<C   : close per-class counts (atomic, zeroed by K0)
//   ws[1 + 2C + blk]     : cls per-block partials (overwritten by K1)

// K0: zero accumulators + compute loss_dist. One block of 256.
// dist identity: sum_j ||w_j - w_i||^2 = sumNorm - 2*dot(w_i, s) + C*||w_i||^2
// where s = sum_j w_j, sumNorm = sum_j ||w_j||^2.
__global__ void k0_zero_dist(const float* __restrict__ w, float* __restrict__ ws,
                             int C, int D) {
    __shared__ float s_vec[128];    // column sums (D == 128)
    __shared__ float s_norm[128];   // per-class norms (C <= 128)
    __shared__ float s_red[4];

    int t = threadIdx.x;

    // zero the atomic accumulators
    for (int i = t; i < 2 * C; i += blockDim.x)
        ws[1 + i] = 0.f;

    if (t < D) {
        float acc = 0.f;
        for (int j = 0; j < C; ++j) acc += w[j * D + t];
        s_vec[t] = acc;
    }
    __syncthreads();

    float norm_i = 0.f, dot_i = 0.f;
    if (t < C) {
        for (int d = 0; d < D; ++d) {
            float v = w[t * D + d];
            norm_i += v * v;
            dot_i  += v * s_vec[d];
        }
    }
    if (t < 128) s_norm[t] = (t < C) ? norm_i : 0.f;
    __syncthreads();

    // sumNorm = reduce(s_norm)
    float sn = (t < 128) ? s_norm[t] : 0.f;
    sn = wave_reduce_sum(sn);
    if ((t & 63) == 0) s_red[t >> 6] = sn;
    __syncthreads();
    float sumNorm = s_red[0] + s_red[1] + s_red[2] + s_red[3];
    __syncthreads();   // s_red reused below

    float contrib = 0.f;
    if (t < C) {
        float S = (sumNorm + (float)C * norm_i - 2.f * dot_i)
                  / ((float)(C - 1) * (float)D);
        contrib = fmaxf(MARGIN - S, 0.f) / (float)C;
    }
    contrib = wave_reduce_sum(contrib);
    if ((t & 63) == 0) s_red[t >> 6] = contrib;
    __syncthreads();
    if (t == 0) ws[0] = s_red[0] + s_red[1] + s_red[2] + s_red[3];
}

// K1: fused close + cls partials. 512 blocks x 256 threads.
__global__ void k1_main(const float* __restrict__ z, const float* __restrict__ w,
                        const float* __restrict__ o, const int* __restrict__ y,
                        float* __restrict__ ws, int B, int C, int D) {
    int t = threadIdx.x;
    int lane = t & 63, wid = t >> 6;

    // ---- close: 4 waves/block, B/(grid*4) samples per wave ----
    int wavesTotal = gridDim.x * 4;
    int gw = blockIdx.x * 4 + wid;
    int spw = B / wavesTotal;                 // 8192/2048 = 4
    for (int k = 0; k < spw; ++k) {
        int b = gw * spw + k;
        int yb = y[b];
        const float2* zp = reinterpret_cast<const float2*>(z + ((size_t)b * C + yb) * D);
        const float2* wp = reinterpret_cast<const float2*>(w + (size_t)yb * D);
        float2 zv = zp[lane];                 // 64 lanes x 8B = 512B coalesced
        float2 wv = wp[lane];
        float d0 = zv.x - wv.x;
        float d1 = zv.y - wv.y;
        float acc = wave_reduce_sum(d0 * d0 + d1 * d1);
        if (lane == 0) {
            atomicAdd(&ws[1 + yb], acc);      // 100 distinct addresses — low contention
            atomicAdd(&ws[1 + C + yb], 1.0f);
        }
    }

    // ---- cls: grid-stride float4, per-block partial (no atomics) ----
    int nq = B * C / 4;                       // C%4==0 -> float4 never crosses a row
    int perRow = C >> 2;
    float acc = 0.f;
    for (int q = blockIdx.x * blockDim.x + t; q < nq; q += gridDim.x * blockDim.x) {
        int b  = q / perRow;
        int c0 = (q - b * perRow) * 4;
        float4 v = reinterpret_cast<const float4*>(o)[q];
        int yb = y[b];
        float e0 = v.x - ((c0 + 0 == yb) ? 1.f : 0.f);
        float e1 = v.y - ((c0 + 1 == yb) ? 1.f : 0.f);
        float e2 = v.z - ((c0 + 2 == yb) ? 1.f : 0.f);
        float e3 = v.w - ((c0 + 3 == yb) ? 1.f : 0.f);
        acc += e0*e0 + e1*e1 + e2*e2 + e3*e3;
    }
    acc = wave_reduce_sum(acc);
    __shared__ float part[4];
    if (lane == 0) part[wid] = acc;
    __syncthreads();
    if (t == 0)
        ws[1 + 2 * C + blockIdx.x] = part[0] + part[1] + part[2] + part[3];
}

// K2: combine. One block of 256.
__global__ void k2_final(const float* __restrict__ ws, float* __restrict__ out,
                         int B, int C, int D, int nblocks) {
    int t = threadIdx.x;
    int lane = t & 63, wid = t >> 6;

    float closeAcc = 0.f;
    for (int c = t; c < C; c += blockDim.x)
        closeAcc += ws[1 + c] / (ws[1 + C + c] * (float)D);

    float clsAcc = 0.f;
    for (int i = t; i < nblocks; i += blockDim.x)
        clsAcc += ws[1 + 2 * C + i];

    closeAcc = wave_reduce_sum(closeAcc);
    clsAcc   = wave_reduce_sum(clsAcc);
    __shared__ float pc[4], pk[4];
    if (lane == 0) { pc[wid] = closeAcc; pk[wid] = clsAcc; }
    __syncthreads();
    if (t == 0) {
        float close = pc[0] + pc[1] + pc[2] + pc[3];
        float cls   = (pk[0] + pk[1] + pk[2] + pk[3]) / ((float)B * (float)C);
        float dist  = ws[0];
        out[0] = cls + close + dist;
        out[1] = cls;
        out[2] = close;
        out[3] = dist;
    }
}

extern "C" void kernel_launch(void* const* d_in, const int* in_sizes, int n_in,
                              void* d_out, int out_size, void* d_ws, size_t ws_size,
                              hipStream_t stream) {
    const float* z = (const float*)d_in[0];
    const float* w = (const float*)d_in[1];
    const float* o = (const float*)d_in[2];
    const int*   y = (const int*)d_in[3];
    float* out = (float*)d_out;
    float* ws  = (float*)d_ws;

    const int B = in_sizes[3];              // 8192
    const int C = in_sizes[2] / B;          // 100
    const int D = in_sizes[1] / C;          // 128
    const int NB = 512;

    k0_zero_dist<<<1, 256, 0, stream>>>(w, ws, C, D);
    k1_main<<<NB, 256, 0, stream>>>(z, w, o, y, ws, B, C, D);
    k2_final<<<1, 256, 0, stream>>>(ws, out, B, C, D, NB);
}

// Round 3
// 22.241 us; speedup vs baseline: 4.5185x; 2.4978x over previous
//
#include <hip/hip_runtime.h>

#define MARGIN 1.0f
#define MAXC 128   // C = 100 at runtime; LDS arrays sized to 128

__device__ __forceinline__ float wave_reduce_sum(float v) {
    #pragma unroll
    for (int off = 32; off > 0; off >>= 1)
        v += __shfl_down(v, off, 64);
    return v;
}

// ws layout (floats):
//   [0,            C*NB)   : closeS[c][blk]  per-class per-block sums (transposed)
//   [C*NB,       2*C*NB)   : closeN[c][blk]  per-class per-block counts
//   [2*C*NB, 2*C*NB + NB)  : cls per-block partials
//   [2*C*NB + NB]          : loss_dist
// Every cell is overwritten each launch -> no zeroing, poison-proof.

// K1: blocks 0..NB-1 do fused close+cls partials; block NB does dist.
__global__ void k1_main(const float* __restrict__ z, const float* __restrict__ w,
                        const float* __restrict__ o, const int* __restrict__ y,
                        float* __restrict__ ws, int B, int C, int D, int NB) {
    int t = threadIdx.x;
    int lane = t & 63, wid = t >> 6;
    int blk = blockIdx.x;

    if (blk == NB) {
        // ---- dist block: S[i] = (sumNorm + C*||w_i||^2 - 2*w_i·s) / ((C-1)*D) ----
        __shared__ float s_vec[128];   // column sums of w (D == 128)
        __shared__ float s_p[256];
        int d = t & 127, half = t >> 7;
        float a = 0.f;
        for (int j = half; j < C; j += 2) a += w[j * D + d];
        s_p[t] = a;
        __syncthreads();
        if (t < 128) s_vec[t] = s_p[t] + s_p[t + 128];
        __syncthreads();

        float norm_i = 0.f, dot_i = 0.f;
        if (t < C) {
            const float4* wp = reinterpret_cast<const float4*>(w + (size_t)t * D);
            for (int q = 0; q < D / 4; ++q) {
                float4 v = wp[q];
                norm_i += v.x*v.x + v.y*v.y + v.z*v.z + v.w*v.w;
                dot_i  += v.x*s_vec[4*q] + v.y*s_vec[4*q+1]
                        + v.z*s_vec[4*q+2] + v.w*s_vec[4*q+3];
            }
        }
        // sumNorm = reduce over classes
        float sn = (t < C) ? norm_i : 0.f;
        sn = wave_reduce_sum(sn);
        __shared__ float s_red[4];
        if (lane == 0) s_red[wid] = sn;
        __syncthreads();
        float sumNorm = s_red[0] + s_red[1] + s_red[2] + s_red[3];
        __syncthreads();

        float contrib = 0.f;
        if (t < C) {
            float S = (sumNorm + (float)C * norm_i - 2.f * dot_i)
                      / ((float)(C - 1) * (float)D);
            contrib = fmaxf(MARGIN - S, 0.f) / (float)C;
        }
        contrib = wave_reduce_sum(contrib);
        if (lane == 0) s_red[wid] = contrib;
        __syncthreads();
        if (t == 0)
            ws[2 * C * NB + NB] = s_red[0] + s_red[1] + s_red[2] + s_red[3];
        return;
    }

    // ---- main blocks ----
    __shared__ float s_sum[MAXC];
    __shared__ float s_cnt[MAXC];
    for (int i = t; i < C; i += blockDim.x) { s_sum[i] = 0.f; s_cnt[i] = 0.f; }
    __syncthreads();

    // close: 4 waves/block, spw samples each, LDS atomics (100 addrs, low contention)
    int gw = blk * 4 + wid;
    int spw = B / (NB * 4);
    for (int k = 0; k < spw; ++k) {
        int b = gw * spw + k;
        int yb = y[b];
        const float2* zp = reinterpret_cast<const float2*>(z + ((size_t)b * C + yb) * D);
        const float2* wp = reinterpret_cast<const float2*>(w + (size_t)yb * D);
        float2 zv = zp[lane];      // 64 lanes x 8B = 512B coalesced
        float2 wv = wp[lane];
        float d0 = zv.x - wv.x;
        float d1 = zv.y - wv.y;
        float acc = wave_reduce_sum(d0 * d0 + d1 * d1);
        if (lane == 0) {
            atomicAdd(&s_sum[yb], acc);
            atomicAdd(&s_cnt[yb], 1.0f);
        }
    }

    // cls: grid-stride float4 over o (C%4==0 -> never crosses a row)
    int nq = B * C / 4;
    int perRow = C >> 2;
    float acc = 0.f;
    for (int q = blk * blockDim.x + t; q < nq; q += NB * blockDim.x) {
        int b  = q / perRow;
        int c0 = (q - b * perRow) * 4;
        float4 v = reinterpret_cast<const float4*>(o)[q];
        int yb = y[b];
        float e0 = v.x - ((c0 + 0 == yb) ? 1.f : 0.f);
        float e1 = v.y - ((c0 + 1 == yb) ? 1.f : 0.f);
        float e2 = v.z - ((c0 + 2 == yb) ? 1.f : 0.f);
        float e3 = v.w - ((c0 + 3 == yb) ? 1.f : 0.f);
        acc += e0*e0 + e1*e1 + e2*e2 + e3*e3;
    }
    acc = wave_reduce_sum(acc);
    __shared__ float part[4];
    if (lane == 0) part[wid] = acc;
    __syncthreads();

    // write per-block partials (transposed: [c][blk] for contiguous K2 reads)
    for (int c = t; c < C; c += blockDim.x) {
        ws[(size_t)c * NB + blk]           = s_sum[c];
        ws[(size_t)(C + c) * NB + blk]     = s_cnt[c];
    }
    if (t == 0)
        ws[2 * C * NB + blk] = part[0] + part[1] + part[2] + part[3];
}

// K2: single block of 256 — reduce partials, combine, write out.
__global__ void k2_final(const float* __restrict__ ws, float* __restrict__ out,
                         int B, int C, int D, int NB) {
    int t = threadIdx.x;
    int lane = t & 63, wid = t >> 6;

    float closeAcc = 0.f;
    if (t < C) {
        const float4* sp = reinterpret_cast<const float4*>(ws + (size_t)t * NB);
        const float4* np = reinterpret_cast<const float4*>(ws + (size_t)(C + t) * NB);
        float s = 0.f, n = 0.f;
        for (int q = 0; q < NB / 4; ++q) {
            float4 a = sp[q], b = np[q];
            s += a.x + a.y + a.z + a.w;
            n += b.x + b.y + b.z + b.w;
        }
        closeAcc = s / (n * (float)D);
    }

    float clsAcc = 0.f;
    for (int i = t; i < NB; i += blockDim.x)
        clsAcc += ws[2 * C * NB + i];

    closeAcc = wave_reduce_sum(closeAcc);
    clsAcc   = wave_reduce_sum(clsAcc);
    __shared__ float pc[4], pk[4];
    if (lane == 0) { pc[wid] = closeAcc; pk[wid] = clsAcc; }
    __syncthreads();
    if (t == 0) {
        float close = pc[0] + pc[1] + pc[2] + pc[3];
        float cls   = (pk[0] + pk[1] + pk[2] + pk[3]) / ((float)B * (float)C);
        float dist  = ws[2 * C * NB + NB];
        out[0] = cls + close + dist;
        out[1] = cls;
        out[2] = close;
        out[3] = dist;
    }
}

extern "C" void kernel_launch(void* const* d_in, const int* in_sizes, int n_in,
                              void* d_out, int out_size, void* d_ws, size_t ws_size,
                              hipStream_t stream) {
    const float* z = (const float*)d_in[0];
    const float* w = (const float*)d_in[1];
    const float* o = (const float*)d_in[2];
    const int*   y = (const int*)d_in[3];
    float* out = (float*)d_out;
    float* ws  = (float*)d_ws;

    const int B = in_sizes[3];              // 8192
    const int C = in_sizes[2] / B;          // 100
    const int D = in_sizes[1] / C;          // 128
    const int NB = 128;

    k1_main<<<NB + 1, 256, 0, stream>>>(z, w, o, y, ws, B, C, D, NB);
    k2_final<<<1, 256, 0, stream>>>(ws, out, B, C, D, NB);
}